// Round 1
// baseline (1752.873 us; speedup 1.0000x reference)
//
#include <hip/hip_runtime.h>
#include <stdint.h>

#define FAN_IN  512
#define FAN_MID 256
#define FAN_OUT 64
#define NEG_SLOPE 0.01f

typedef __bf16 bf16_t;
typedef bf16_t bf16x8 __attribute__((ext_vector_type(8)));
typedef float  f32x4  __attribute__((ext_vector_type(4)));
typedef unsigned short u16x8 __attribute__((ext_vector_type(8)));

__device__ inline unsigned short f2b(float f) {
    union { float f; unsigned int u; } v; v.f = f;
    unsigned int u = v.u;
    return (unsigned short)((u + 0x7fffu + ((u >> 16) & 1u)) >> 16); // RNE
}

// ---------------- CSR build ----------------
__global__ void zero_kernel(int* p, int n) {
    int i = blockIdx.x * 256 + threadIdx.x;
    if (i < n) p[i] = 0;
}

__global__ void hist_kernel(const int* __restrict__ dst, int* __restrict__ counts, int E) {
    int e = blockIdx.x * 256 + threadIdx.x;
    if (e < E) atomicAdd(&counts[dst[e]], 1);
}

__global__ void scan_kernel(const int* __restrict__ counts, int* __restrict__ offsets,
                            int* __restrict__ cursor, int N, int E) {
    __shared__ int part[1024];
    int t = threadIdx.x;
    int chunk = (N + 1023) >> 10;
    int s = t * chunk;
    int e = s + chunk; if (e > N) e = N;
    int sum = 0;
    for (int i = s; i < e; i++) sum += counts[i];
    part[t] = sum;
    __syncthreads();
    for (int off = 1; off < 1024; off <<= 1) {
        int v = (t >= off) ? part[t - off] : 0;
        __syncthreads();
        part[t] += v;
        __syncthreads();
    }
    int run = (t == 0) ? 0 : part[t - 1];
    for (int i = s; i < e; i++) {
        offsets[i] = run; cursor[i] = run;
        run += counts[i];
    }
    if (t == 1023) offsets[N] = E;
}

__global__ void fill_kernel(const int* __restrict__ src, const int* __restrict__ dst,
                            const float* __restrict__ w1, const float* __restrict__ w2,
                            int* __restrict__ cursor, int* __restrict__ csr_src,
                            float* __restrict__ csr_w1, float* __restrict__ csr_w2, int E) {
    int e = blockIdx.x * 256 + threadIdx.x;
    if (e >= E) return;
    int d = dst[e];
    int pos = atomicAdd(&cursor[d], 1);
    csr_src[pos] = src[e];
    csr_w1[pos]  = w1[e];
    csr_w2[pos]  = w2[e];
}

// ---------------- weight transpose + bf16 convert: Wt[n][k] = bf16(W[k][n]) ----------------
__global__ void convert_w_kernel(const float* __restrict__ W, unsigned short* __restrict__ Wt,
                                 int K, int N) {
    int idx = blockIdx.x * 256 + threadIdx.x;
    if (idx >= K * N) return;
    int k = idx / N, n = idx % N;
    Wt[(size_t)n * K + k] = f2b(W[idx]);
}

// ---------------- bf16 MFMA GEMM: C[M,N] = A[M,K] * Bt[N,K]^T ----------------
// 64x64 tile, 256 threads = 4 waves, wave w -> rows [w*16, w*16+16), BK=32.
// MFMA 16x16x32 bf16. A frag: A[m=lane&15][k=(lane>>4)*8+j]; B frag: B[n=lane&15][k=quad*8+j];
// D: col=lane&15, row=(lane>>4)*4+reg (m89/m91-verified mapping).
template<int K, bool A_F32>
__global__ __launch_bounds__(256) void gemm_bt(const void* __restrict__ Ap,
                                               const unsigned short* __restrict__ Bt,
                                               float* __restrict__ C, int M, int N) {
    constexpr int LDT = 40;            // padded LDS stride in ushorts (80 B = 16B-aligned rows, conflict-light)
    __shared__ unsigned short As[64 * LDT];
    __shared__ unsigned short Bs[64 * LDT];
    const int m0 = blockIdx.x * 64;
    const int n0 = blockIdx.y * 64;
    const int tid  = threadIdx.x;
    const int lane = tid & 63;
    const int w    = tid >> 6;
    const int lrow = tid >> 2;          // 0..63
    const int lseg = (tid & 3) * 8;     // 0,8,16,24
    const int q  = lane >> 4;
    const int mm = lane & 15;

    f32x4 acc[4] = {};

    for (int k0 = 0; k0 < K; k0 += 32) {
        __syncthreads();
        // A tile: 64 rows x 32 cols bf16
        {
            int gm = m0 + lrow;
            u16x8 av;
            if (A_F32) {
                const float* A32 = (const float*)Ap;
                if (gm < M) {
                    const float4* pp = (const float4*)(A32 + (size_t)gm * K + k0 + lseg);
                    float4 f0 = pp[0], f1 = pp[1];
                    av[0] = f2b(f0.x); av[1] = f2b(f0.y); av[2] = f2b(f0.z); av[3] = f2b(f0.w);
                    av[4] = f2b(f1.x); av[5] = f2b(f1.y); av[6] = f2b(f1.z); av[7] = f2b(f1.w);
                } else {
                    av = (u16x8)0;
                }
            } else {
                const unsigned short* A16 = (const unsigned short*)Ap;
                if (gm < M) av = *(const u16x8*)(A16 + (size_t)gm * K + k0 + lseg);
                else        av = (u16x8)0;
            }
            *(u16x8*)&As[lrow * LDT + lseg] = av;
        }
        // B tile: 64 n-rows x 32 k-cols (Bt is [N][K] row-major; N,K multiples of tile)
        *(u16x8*)&Bs[lrow * LDT + lseg] =
            *(const u16x8*)(Bt + (size_t)(n0 + lrow) * K + k0 + lseg);
        __syncthreads();

        bf16x8 a = *(const bf16x8*)&As[(w * 16 + mm) * LDT + q * 8];
#pragma unroll
        for (int t = 0; t < 4; t++) {
            bf16x8 b = *(const bf16x8*)&Bs[(t * 16 + mm) * LDT + q * 8];
            acc[t] = __builtin_amdgcn_mfma_f32_16x16x32_bf16(a, b, acc[t], 0, 0, 0);
        }
    }

#pragma unroll
    for (int t = 0; t < 4; t++) {
#pragma unroll
        for (int r = 0; r < 4; r++) {
            int row = m0 + w * 16 + q * 4 + r;
            if (row < M) C[(size_t)row * N + n0 + t * 16 + mm] = acc[t][r];
        }
    }
}

// ---------------- aggregation layer 1: h = bf16(leaky_relu(segsum(w * support1[src]) + b1)) ----------------
// one wave per node; lane covers 4 of 256 features via float4
__global__ __launch_bounds__(256) void agg1_kernel(const float* __restrict__ support,
                                                   const int* __restrict__ offsets,
                                                   const int* __restrict__ csr_src,
                                                   const float* __restrict__ csr_w,
                                                   const float* __restrict__ b1,
                                                   unsigned short* __restrict__ h, int Nn) {
    int wave = threadIdx.x >> 6;
    int lane = threadIdx.x & 63;
    int node = blockIdx.x * 4 + wave;
    if (node >= Nn) return;
    int s = offsets[node], e = offsets[node + 1];
    float a0 = 0.f, a1 = 0.f, a2 = 0.f, a3 = 0.f;
    const float4* S = (const float4*)support;
    for (int i = s; i < e; i++) {
        int src = csr_src[i];
        float w = csr_w[i];
        float4 v = S[(size_t)src * 64 + lane];
        a0 += w * v.x; a1 += w * v.y; a2 += w * v.z; a3 += w * v.w;
    }
    float4 bb = ((const float4*)b1)[lane];
    float r0 = a0 + bb.x, r1 = a1 + bb.y, r2 = a2 + bb.z, r3 = a3 + bb.w;
    r0 = r0 > 0.f ? r0 : r0 * NEG_SLOPE;
    r1 = r1 > 0.f ? r1 : r1 * NEG_SLOPE;
    r2 = r2 > 0.f ? r2 : r2 * NEG_SLOPE;
    r3 = r3 > 0.f ? r3 : r3 * NEG_SLOPE;
    ushort4 o;
    o.x = f2b(r0); o.y = f2b(r1); o.z = f2b(r2); o.w = f2b(r3);
    *(ushort4*)&h[(size_t)node * 256 + lane * 4] = o;
}

// ---------------- aggregation layer 2 + bias + log_softmax ----------------
// one wave per node; lane = feature (64)
__global__ __launch_bounds__(256) void agg2_kernel(const float* __restrict__ support,
                                                   const int* __restrict__ offsets,
                                                   const int* __restrict__ csr_src,
                                                   const float* __restrict__ csr_w,
                                                   const float* __restrict__ b2,
                                                   float* __restrict__ out, int Nn) {
    int wave = threadIdx.x >> 6;
    int lane = threadIdx.x & 63;
    int node = blockIdx.x * 4 + wave;
    if (node >= Nn) return;
    int s = offsets[node], e = offsets[node + 1];
    float acc = 0.f;
    for (int i = s; i < e; i++) {
        int src = csr_src[i];
        float w = csr_w[i];
        acc += w * support[(size_t)src * 64 + lane];
    }
    float logit = acc + b2[lane];
    float m = logit;
    for (int off = 32; off; off >>= 1) m = fmaxf(m, __shfl_xor(m, off));
    float ex = expf(logit - m);
    float sum = ex;
    for (int off = 32; off; off >>= 1) sum += __shfl_xor(sum, off);
    out[(size_t)node * 64 + lane] = logit - m - logf(sum);
}

// ---------------- launch ----------------
extern "C" void kernel_launch(void* const* d_in, const int* in_sizes, int n_in,
                              void* d_out, int out_size, void* d_ws, size_t ws_size,
                              hipStream_t stream) {
    const float* x   = (const float*)d_in[0];
    const int*   esrc = (const int*)d_in[1];
    const int*   edst = (const int*)d_in[2];
    const float* ew1 = (const float*)d_in[3];
    const float* ew2 = (const float*)d_in[4];
    const float* W1  = (const float*)d_in[5];
    const float* b1  = (const float*)d_in[6];
    const float* W2  = (const float*)d_in[7];
    const float* b2  = (const float*)d_in[8];
    float* out = (float*)d_out;
    const int Nn = in_sizes[0] / FAN_IN;   // 100000
    const int E  = in_sizes[1];            // 3200000

    char* p = (char*)d_ws;
    auto alloc = [&](size_t bytes) -> char* {
        char* r = p;
        p += (bytes + 255) & ~(size_t)255;
        return r;
    };
    float*          support1 = (float*)alloc((size_t)Nn * FAN_MID * 4);   // 102.4 MB
    unsigned short* h        = (unsigned short*)alloc((size_t)Nn * FAN_MID * 2); // 51.2 MB
    float*          support2 = (float*)alloc((size_t)Nn * FAN_OUT * 4);   // 25.6 MB
    unsigned short* W1t      = (unsigned short*)alloc((size_t)FAN_IN * FAN_MID * 2);
    unsigned short* W2t      = (unsigned short*)alloc((size_t)FAN_MID * FAN_OUT * 2);
    int*            counts   = (int*)alloc((size_t)Nn * 4);
    int*            offsets  = (int*)alloc(((size_t)Nn + 1) * 4);
    int*            cursor   = (int*)alloc((size_t)Nn * 4);
    int*            csr_src  = (int*)alloc((size_t)E * 4);
    float*          csr_w1   = (float*)alloc((size_t)E * 4);
    float*          csr_w2   = (float*)alloc((size_t)E * 4);
    // total ~209 MB

    // CSR build (graph is shared by both layers)
    zero_kernel<<<(Nn + 255) / 256, 256, 0, stream>>>(counts, Nn);
    hist_kernel<<<(E + 255) / 256, 256, 0, stream>>>(edst, counts, E);
    scan_kernel<<<1, 1024, 0, stream>>>(counts, offsets, cursor, Nn, E);
    fill_kernel<<<(E + 255) / 256, 256, 0, stream>>>(esrc, edst, ew1, ew2, cursor,
                                                     csr_src, csr_w1, csr_w2, E);
    // weights: transpose + bf16
    convert_w_kernel<<<(FAN_IN * FAN_MID + 255) / 256, 256, 0, stream>>>(W1, W1t, FAN_IN, FAN_MID);
    convert_w_kernel<<<(FAN_MID * FAN_OUT + 255) / 256, 256, 0, stream>>>(W2, W2t, FAN_MID, FAN_OUT);

    // layer 1: support1 = x @ W1 (bf16 MFMA, fp32 A converted in-kernel)
    gemm_bt<FAN_IN, true><<<dim3((Nn + 63) / 64, FAN_MID / 64), 256, 0, stream>>>(
        x, W1t, support1, Nn, FAN_MID);
    agg1_kernel<<<(Nn + 3) / 4, 256, 0, stream>>>(support1, offsets, csr_src, csr_w1, b1, h, Nn);

    // layer 2: support2 = h @ W2
    gemm_bt<FAN_MID, false><<<dim3((Nn + 63) / 64, FAN_OUT / 64), 256, 0, stream>>>(
        h, W2t, support2, Nn, FAN_OUT);
    agg2_kernel<<<(Nn + 3) / 4, 256, 0, stream>>>(support2, offsets, csr_src, csr_w2, b2, out, Nn);
}

// Round 2
// 1282.741 us; speedup vs baseline: 1.3665x; 1.3665x over previous
//
#include <hip/hip_runtime.h>
#include <stdint.h>

#define FAN_IN  512
#define FAN_MID 256
#define FAN_OUT 64
#define NEG_SLOPE 0.01f

typedef __bf16 bf16_t;
typedef bf16_t bf16x8 __attribute__((ext_vector_type(8)));
typedef float  f32x4  __attribute__((ext_vector_type(4)));
typedef unsigned short u16x8 __attribute__((ext_vector_type(8)));

__device__ inline unsigned short f2b(float f) {
    union { float f; unsigned int u; } v; v.f = f;
    unsigned int u = v.u;
    return (unsigned short)((u + 0x7fffu + ((u >> 16) & 1u)) >> 16); // RNE
}
__device__ inline float b2f(unsigned short u) {
    union { unsigned int u; float f; } v; v.u = ((unsigned int)u) << 16; return v.f;
}

// ---------------- CSR build ----------------
__global__ void zero_kernel(int* p, int n) {
    int i = blockIdx.x * 256 + threadIdx.x;
    if (i < n) p[i] = 0;
}

__global__ void hist_kernel(const int* __restrict__ dst, int* __restrict__ counts, int E) {
    int e = blockIdx.x * 256 + threadIdx.x;
    if (e < E) atomicAdd(&counts[dst[e]], 1);
}

__global__ void scan_kernel(const int* __restrict__ counts, int* __restrict__ offsets,
                            int* __restrict__ cursor, int N, int E) {
    __shared__ int part[1024];
    int t = threadIdx.x;
    int chunk = (N + 1023) >> 10;
    int s = t * chunk;
    int e = s + chunk; if (e > N) e = N;
    int sum = 0;
    for (int i = s; i < e; i++) sum += counts[i];
    part[t] = sum;
    __syncthreads();
    for (int off = 1; off < 1024; off <<= 1) {
        int v = (t >= off) ? part[t - off] : 0;
        __syncthreads();
        part[t] += v;
        __syncthreads();
    }
    int run = (t == 0) ? 0 : part[t - 1];
    for (int i = s; i < e; i++) {
        offsets[i] = run; cursor[i] = run;
        run += counts[i];
    }
    if (t == 1023) offsets[N] = E;
}

// CSR record: {src, w1_f32_bits, w2_f32_bits, pad} — one aligned 16B scatter
__global__ void fill_kernel(const int* __restrict__ src, const int* __restrict__ dst,
                            const float* __restrict__ w1, const float* __restrict__ w2,
                            int* __restrict__ cursor, uint4* __restrict__ csr, int E) {
    int e = blockIdx.x * 256 + threadIdx.x;
    if (e >= E) return;
    int d = dst[e];
    int pos = atomicAdd(&cursor[d], 1);
    uint4 v;
    v.x = (unsigned int)src[e];
    v.y = __float_as_uint(w1[e]);
    v.z = __float_as_uint(w2[e]);
    v.w = 0;
    csr[pos] = v;
}

// ---------------- weight transpose + bf16 convert: Wt[n][k] = bf16(W[k][n]) ----------------
__global__ void convert_w_kernel(const float* __restrict__ W, unsigned short* __restrict__ Wt,
                                 int K, int N) {
    int idx = blockIdx.x * 256 + threadIdx.x;
    if (idx >= K * N) return;
    int k = idx / N, n = idx % N;
    Wt[(size_t)n * K + k] = f2b(W[idx]);
}

// ---------------- bf16 MFMA GEMM: C[M,N] = A[M,K] * Bt[N,K]^T, C in bf16 ----------------
// One block = 64 rows x N cols (A read exactly ONCE from global).
// 256 threads = 4 waves; wave w owns n-slab [w*(N/4), w*(N/4)+N/4), 4 m-subtiles x NW n-subtiles.
// MFMA 16x16x32 bf16; frag mappings m89/m91-verified (carried from passing R1 kernel).
template<int K, int N, bool A_F32>
__global__ __launch_bounds__(256) void gemm_bt(const void* __restrict__ Ap,
                                               const unsigned short* __restrict__ Bt,
                                               unsigned short* __restrict__ C, int M) {
    constexpr int LDT = 40;          // padded LDS row stride (ushorts)
    constexpr int NW  = N / 64;      // 16-wide n-subtiles per wave
    __shared__ unsigned short As[64 * LDT];
    __shared__ unsigned short Bs[N * LDT];
    const int m0   = blockIdx.x * 64;
    const int tid  = threadIdx.x;
    const int lane = tid & 63;
    const int w    = tid >> 6;
    const int lrow = tid >> 2;       // 0..63
    const int lseg = (tid & 3) * 8;  // 0,8,16,24
    const int q    = lane >> 4;
    const int mm   = lane & 15;

    f32x4 acc[4][NW] = {};

    for (int k0 = 0; k0 < K; k0 += 32) {
        __syncthreads();
        // A tile: 64 rows x 32 k (convert fp32->bf16 inline if needed)
        {
            int gm = m0 + lrow;
            u16x8 av;
            if (A_F32) {
                const float* A32 = (const float*)Ap;
                if (gm < M) {
                    const float4* pp = (const float4*)(A32 + (size_t)gm * K + k0 + lseg);
                    float4 f0 = pp[0], f1 = pp[1];
                    av[0] = f2b(f0.x); av[1] = f2b(f0.y); av[2] = f2b(f0.z); av[3] = f2b(f0.w);
                    av[4] = f2b(f1.x); av[5] = f2b(f1.y); av[6] = f2b(f1.z); av[7] = f2b(f1.w);
                } else av = (u16x8)0;
            } else {
                const unsigned short* A16 = (const unsigned short*)Ap;
                if (gm < M) av = *(const u16x8*)(A16 + (size_t)gm * K + k0 + lseg);
                else        av = (u16x8)0;
            }
            *(u16x8*)&As[lrow * LDT + lseg] = av;
        }
        // B tile: N rows x 32 k
#pragma unroll
        for (int r = 0; r < N / 64; r++) {
            int nr = r * 64 + lrow;
            *(u16x8*)&Bs[nr * LDT + lseg] =
                *(const u16x8*)(Bt + (size_t)nr * K + k0 + lseg);
        }
        __syncthreads();

        bf16x8 a[4], b[NW];
#pragma unroll
        for (int mi = 0; mi < 4; mi++)
            a[mi] = *(const bf16x8*)&As[(mi * 16 + mm) * LDT + q * 8];
#pragma unroll
        for (int ni = 0; ni < NW; ni++)
            b[ni] = *(const bf16x8*)&Bs[(w * NW * 16 + ni * 16 + mm) * LDT + q * 8];
#pragma unroll
        for (int mi = 0; mi < 4; mi++)
#pragma unroll
            for (int ni = 0; ni < NW; ni++)
                acc[mi][ni] = __builtin_amdgcn_mfma_f32_16x16x32_bf16(a[mi], b[ni], acc[mi][ni], 0, 0, 0);
    }

#pragma unroll
    for (int mi = 0; mi < 4; mi++)
#pragma unroll
        for (int ni = 0; ni < NW; ni++)
#pragma unroll
            for (int r = 0; r < 4; r++) {
                int row = m0 + mi * 16 + q * 4 + r;
                if (row < M)
                    C[(size_t)row * N + w * NW * 16 + ni * 16 + mm] = f2b(acc[mi][ni][r]);
            }
}

// ---------------- aggregation layer 1 ----------------
// h = bf16(leaky_relu(segsum(w1 * support1[src]) + b1)); support1 bf16 [N,256]
// one wave per node; lane covers 4 features via ushort4
__global__ __launch_bounds__(256) void agg1_kernel(const unsigned short* __restrict__ S,
                                                   const int* __restrict__ offsets,
                                                   const uint4* __restrict__ edges,
                                                   const float* __restrict__ b1,
                                                   unsigned short* __restrict__ h, int Nn) {
    int wave = threadIdx.x >> 6;
    int lane = threadIdx.x & 63;
    int node = blockIdx.x * 4 + wave;
    if (node >= Nn) return;
    int s = offsets[node], e = offsets[node + 1];
    float a0 = 0.f, a1 = 0.f, a2 = 0.f, a3 = 0.f;
    int i = s;
    for (; i + 4 <= e; i += 4) {
        uint4 e0 = edges[i], e1 = edges[i + 1], e2 = edges[i + 2], e3 = edges[i + 3];
        ushort4 v0 = *(const ushort4*)(S + (size_t)e0.x * 256 + lane * 4);
        ushort4 v1 = *(const ushort4*)(S + (size_t)e1.x * 256 + lane * 4);
        ushort4 v2 = *(const ushort4*)(S + (size_t)e2.x * 256 + lane * 4);
        ushort4 v3 = *(const ushort4*)(S + (size_t)e3.x * 256 + lane * 4);
        float w0 = __uint_as_float(e0.y), w1 = __uint_as_float(e1.y);
        float w2 = __uint_as_float(e2.y), w3 = __uint_as_float(e3.y);
        a0 += w0 * b2f(v0.x) + w1 * b2f(v1.x) + w2 * b2f(v2.x) + w3 * b2f(v3.x);
        a1 += w0 * b2f(v0.y) + w1 * b2f(v1.y) + w2 * b2f(v2.y) + w3 * b2f(v3.y);
        a2 += w0 * b2f(v0.z) + w1 * b2f(v1.z) + w2 * b2f(v2.z) + w3 * b2f(v3.z);
        a3 += w0 * b2f(v0.w) + w1 * b2f(v1.w) + w2 * b2f(v2.w) + w3 * b2f(v3.w);
    }
    for (; i < e; i++) {
        uint4 ev = edges[i];
        float w = __uint_as_float(ev.y);
        ushort4 v = *(const ushort4*)(S + (size_t)ev.x * 256 + lane * 4);
        a0 += w * b2f(v.x); a1 += w * b2f(v.y); a2 += w * b2f(v.z); a3 += w * b2f(v.w);
    }
    float4 bb = ((const float4*)b1)[lane];
    float r0 = a0 + bb.x, r1 = a1 + bb.y, r2 = a2 + bb.z, r3 = a3 + bb.w;
    r0 = r0 > 0.f ? r0 : r0 * NEG_SLOPE;
    r1 = r1 > 0.f ? r1 : r1 * NEG_SLOPE;
    r2 = r2 > 0.f ? r2 : r2 * NEG_SLOPE;
    r3 = r3 > 0.f ? r3 : r3 * NEG_SLOPE;
    ushort4 o;
    o.x = f2b(r0); o.y = f2b(r1); o.z = f2b(r2); o.w = f2b(r3);
    *(ushort4*)&h[(size_t)node * 256 + lane * 4] = o;
}

// ---------------- aggregation layer 2 + bias + log_softmax ----------------
// support2 bf16 [N,64]; one wave per node; lane = feature
__global__ __launch_bounds__(256) void agg2_kernel(const unsigned short* __restrict__ S,
                                                   const int* __restrict__ offsets,
                                                   const uint4* __restrict__ edges,
                                                   const float* __restrict__ b2,
                                                   float* __restrict__ out, int Nn) {
    int wave = threadIdx.x >> 6;
    int lane = threadIdx.x & 63;
    int node = blockIdx.x * 4 + wave;
    if (node >= Nn) return;
    int s = offsets[node], e = offsets[node + 1];
    float acc = 0.f;
    int i = s;
    for (; i + 4 <= e; i += 4) {
        uint4 e0 = edges[i], e1 = edges[i + 1], e2 = edges[i + 2], e3 = edges[i + 3];
        float v0 = b2f(S[(size_t)e0.x * 64 + lane]);
        float v1 = b2f(S[(size_t)e1.x * 64 + lane]);
        float v2 = b2f(S[(size_t)e2.x * 64 + lane]);
        float v3 = b2f(S[(size_t)e3.x * 64 + lane]);
        acc += __uint_as_float(e0.z) * v0 + __uint_as_float(e1.z) * v1
             + __uint_as_float(e2.z) * v2 + __uint_as_float(e3.z) * v3;
    }
    for (; i < e; i++) {
        uint4 ev = edges[i];
        acc += __uint_as_float(ev.z) * b2f(S[(size_t)ev.x * 64 + lane]);
    }
    float logit = acc + b2[lane];
    float m = logit;
    for (int off = 32; off; off >>= 1) m = fmaxf(m, __shfl_xor(m, off));
    float ex = expf(logit - m);
    float sum = ex;
    for (int off = 32; off; off >>= 1) sum += __shfl_xor(sum, off);
    out[(size_t)node * 64 + lane] = logit - m - logf(sum);
}

// ---------------- launch ----------------
extern "C" void kernel_launch(void* const* d_in, const int* in_sizes, int n_in,
                              void* d_out, int out_size, void* d_ws, size_t ws_size,
                              hipStream_t stream) {
    const float* x    = (const float*)d_in[0];
    const int*   esrc = (const int*)d_in[1];
    const int*   edst = (const int*)d_in[2];
    const float* ew1  = (const float*)d_in[3];
    const float* ew2  = (const float*)d_in[4];
    const float* W1   = (const float*)d_in[5];
    const float* b1   = (const float*)d_in[6];
    const float* W2   = (const float*)d_in[7];
    const float* b2   = (const float*)d_in[8];
    float* out = (float*)d_out;
    const int Nn = in_sizes[0] / FAN_IN;   // 100000
    const int E  = in_sizes[1];            // 3200000

    char* p = (char*)d_ws;
    auto alloc = [&](size_t bytes) -> char* {
        char* r = p;
        p += (bytes + 255) & ~(size_t)255;
        return r;
    };
    unsigned short* support1 = (unsigned short*)alloc((size_t)Nn * FAN_MID * 2);  // 51.2 MB
    unsigned short* h        = (unsigned short*)alloc((size_t)Nn * FAN_MID * 2);  // 51.2 MB
    unsigned short* support2 = (unsigned short*)alloc((size_t)Nn * FAN_OUT * 2);  // 12.8 MB
    unsigned short* W1t      = (unsigned short*)alloc((size_t)FAN_IN * FAN_MID * 2);
    unsigned short* W2t      = (unsigned short*)alloc((size_t)FAN_MID * FAN_OUT * 2);
    int*            counts   = (int*)alloc((size_t)Nn * 4);
    int*            offsets  = (int*)alloc(((size_t)Nn + 1) * 4);
    int*            cursor   = (int*)alloc((size_t)Nn * 4);
    uint4*          csr      = (uint4*)alloc((size_t)E * 16);                      // 51.2 MB
    // total ~168 MB

    // CSR build (graph shared by both layers)
    zero_kernel<<<(Nn + 255) / 256, 256, 0, stream>>>(counts, Nn);
    hist_kernel<<<(E + 255) / 256, 256, 0, stream>>>(edst, counts, E);
    scan_kernel<<<1, 1024, 0, stream>>>(counts, offsets, cursor, Nn, E);
    fill_kernel<<<(E + 255) / 256, 256, 0, stream>>>(esrc, edst, ew1, ew2, cursor, csr, E);
    // weights: transpose + bf16
    convert_w_kernel<<<(FAN_IN * FAN_MID + 255) / 256, 256, 0, stream>>>(W1, W1t, FAN_IN, FAN_MID);
    convert_w_kernel<<<(FAN_MID * FAN_OUT + 255) / 256, 256, 0, stream>>>(W2, W2t, FAN_MID, FAN_OUT);

    // layer 1: support1 = bf16(x @ W1); x read once (block covers full N=256)
    gemm_bt<FAN_IN, FAN_MID, true><<<dim3((Nn + 63) / 64, 1), 256, 0, stream>>>(
        x, W1t, support1, Nn);
    agg1_kernel<<<(Nn + 3) / 4, 256, 0, stream>>>(support1, offsets, csr, b1, h, Nn);

    // layer 2: support2 = bf16(h @ W2)
    gemm_bt<FAN_MID, FAN_OUT, false><<<dim3((Nn + 63) / 64, 1), 256, 0, stream>>>(
        h, W2t, support2, Nn);
    agg2_kernel<<<(Nn + 3) / 4, 256, 0, stream>>>(support2, offsets, csr, b2, out, Nn);
}

// Round 3
// 985.229 us; speedup vs baseline: 1.7792x; 1.3020x over previous
//
#include <hip/hip_runtime.h>
#include <stdint.h>

#define FAN_IN  512
#define FAN_MID 256
#define FAN_OUT 64
#define NEG_SLOPE 0.01f
#define NPB 64          // nodes per bucket (bucket = dst >> 6)
#define CURPAD 16       // ints of padding per bucket cursor (64B line each)

typedef __bf16 bf16_t;
typedef bf16_t bf16x8 __attribute__((ext_vector_type(8)));
typedef float  f32x4  __attribute__((ext_vector_type(4)));
typedef unsigned short u16x8 __attribute__((ext_vector_type(8)));

__device__ inline unsigned short f2b(float f) {
    union { float f; unsigned int u; } v; v.f = f;
    unsigned int u = v.u;
    return (unsigned short)((u + 0x7fffu + ((u >> 16) & 1u)) >> 16); // RNE
}
__device__ inline float b2f(unsigned short u) {
    union { unsigned int u; float f; } v; v.u = ((unsigned int)u) << 16; return v.f;
}

// ---------------- bucketed CSR build ----------------
__global__ void zerob_kernel(int* p, int n) {
    int i = blockIdx.x * 256 + threadIdx.x;
    if (i < n) p[i] = 0;
}

// per-block LDS histogram of bucket ids, flushed with global atomics
__global__ __launch_bounds__(256) void bhist_kernel(const int* __restrict__ dst,
                                                    int* __restrict__ bcount, int E, int nb) {
    __shared__ int lc[2048];
    for (int i = threadIdx.x; i < nb; i += 256) lc[i] = 0;
    __syncthreads();
    int stride = gridDim.x * 256;
    for (int e = blockIdx.x * 256 + threadIdx.x; e < E; e += stride)
        atomicAdd(&lc[dst[e] >> 6], 1);
    __syncthreads();
    for (int i = threadIdx.x; i < nb; i += 256)
        if (lc[i]) atomicAdd(&bcount[i], lc[i]);
}

// single-block scan over bucket counts -> bucket offsets + padded cursors
__global__ void bscan_kernel(const int* __restrict__ bcount, int* __restrict__ boff,
                             int* __restrict__ bcur, int nb, int E) {
    __shared__ int part[1024];
    int t = threadIdx.x;
    int chunk = (nb + 1023) >> 10;
    int s = t * chunk;
    int e = s + chunk; if (e > nb) e = nb;
    int sum = 0;
    for (int i = s; i < e; i++) sum += bcount[i];
    part[t] = sum;
    __syncthreads();
    for (int off = 1; off < 1024; off <<= 1) {
        int v = (t >= off) ? part[t - off] : 0;
        __syncthreads();
        part[t] += v;
        __syncthreads();
    }
    int run = (t == 0) ? 0 : part[t - 1];
    for (int i = s; i < e; i++) {
        boff[i] = run;
        bcur[i * CURPAD] = run;
        run += bcount[i];
    }
    if (t == 1023) boff[nb] = E;
}

// append each edge record into its bucket region (consecutive positions -> full lines)
__global__ __launch_bounds__(256) void bscatter_kernel(const int* __restrict__ src,
                                                       const int* __restrict__ dst,
                                                       const float* __restrict__ w1,
                                                       const float* __restrict__ w2,
                                                       int* __restrict__ bcur,
                                                       uint4* __restrict__ bstage, int E) {
    int e = blockIdx.x * 256 + threadIdx.x;
    if (e >= E) return;
    int d = dst[e];
    int b = d >> 6;
    int pos = atomicAdd(&bcur[b * CURPAD], 1);
    uint4 v;
    v.x = (unsigned int)src[e];
    v.y = __float_as_uint(w1[e]);
    v.z = __float_as_uint(w2[e]);
    v.w = (unsigned int)d;
    bstage[pos] = v;
}

// one block per bucket: LDS count+scan (emits offsets[] for free), local re-scatter.
// Write window per block ~32KB -> L2-coalesced, no line amplification.
__global__ __launch_bounds__(256) void bsort_kernel(const uint4* __restrict__ bstage,
                                                    const int* __restrict__ boff,
                                                    int* __restrict__ offsets,
                                                    uint4* __restrict__ csr,
                                                    int Nn, int E, int nb) {
    __shared__ int cnt[NPB];
    __shared__ int scn[NPB];
    __shared__ int cur[NPB];
    int b = blockIdx.x;
    int t = threadIdx.x;
    int base = boff[b], end = boff[b + 1];
    int n0 = b * NPB;
    if (t < NPB) cnt[t] = 0;
    __syncthreads();
    for (int i = base + t; i < end; i += 256)
        atomicAdd(&cnt[bstage[i].w - n0], 1);
    __syncthreads();
    if (t == 0) {
        int run = 0;
        for (int j = 0; j < NPB; j++) { scn[j] = run; run += cnt[j]; }
    }
    __syncthreads();
    if (t < NPB) {
        cur[t] = scn[t];
        int n = n0 + t;
        if (n < Nn) offsets[n] = base + scn[t];
    }
    if (b == nb - 1 && t == 0) offsets[Nn] = E;
    __syncthreads();
    for (int i = base + t; i < end; i += 256) {
        uint4 rec = bstage[i];
        int lp = atomicAdd(&cur[rec.w - n0], 1);
        csr[base + lp] = rec;
    }
}

// ---------------- weight transpose + bf16 convert: Wt[n][k] = bf16(W[k][n]) ----------------
__global__ void convert_w_kernel(const float* __restrict__ W, unsigned short* __restrict__ Wt,
                                 int K, int N) {
    int idx = blockIdx.x * 256 + threadIdx.x;
    if (idx >= K * N) return;
    int k = idx / N, n = idx % N;
    Wt[(size_t)n * K + k] = f2b(W[idx]);
}

// ---------------- bf16 MFMA GEMM: C[M,N] = A[M,K] * Bt[N,K]^T, C in bf16 ----------------
// One block = 64 rows x N cols (A read exactly ONCE from global).
// 256 threads = 4 waves; wave w owns n-slab, 4 m-subtiles x NW n-subtiles.
template<int K, int N, bool A_F32>
__global__ __launch_bounds__(256) void gemm_bt(const void* __restrict__ Ap,
                                               const unsigned short* __restrict__ Bt,
                                               unsigned short* __restrict__ C, int M) {
    constexpr int LDT = 40;
    constexpr int NW  = N / 64;
    __shared__ unsigned short As[64 * LDT];
    __shared__ unsigned short Bs[N * LDT];
    const int m0   = blockIdx.x * 64;
    const int tid  = threadIdx.x;
    const int lane = tid & 63;
    const int w    = tid >> 6;
    const int lrow = tid >> 2;
    const int lseg = (tid & 3) * 8;
    const int q    = lane >> 4;
    const int mm   = lane & 15;

    f32x4 acc[4][NW] = {};

    for (int k0 = 0; k0 < K; k0 += 32) {
        __syncthreads();
        {
            int gm = m0 + lrow;
            u16x8 av;
            if (A_F32) {
                const float* A32 = (const float*)Ap;
                if (gm < M) {
                    const float4* pp = (const float4*)(A32 + (size_t)gm * K + k0 + lseg);
                    float4 f0 = pp[0], f1 = pp[1];
                    av[0] = f2b(f0.x); av[1] = f2b(f0.y); av[2] = f2b(f0.z); av[3] = f2b(f0.w);
                    av[4] = f2b(f1.x); av[5] = f2b(f1.y); av[6] = f2b(f1.z); av[7] = f2b(f1.w);
                } else av = (u16x8)0;
            } else {
                const unsigned short* A16 = (const unsigned short*)Ap;
                if (gm < M) av = *(const u16x8*)(A16 + (size_t)gm * K + k0 + lseg);
                else        av = (u16x8)0;
            }
            *(u16x8*)&As[lrow * LDT + lseg] = av;
        }
#pragma unroll
        for (int r = 0; r < N / 64; r++) {
            int nr = r * 64 + lrow;
            *(u16x8*)&Bs[nr * LDT + lseg] =
                *(const u16x8*)(Bt + (size_t)nr * K + k0 + lseg);
        }
        __syncthreads();

        bf16x8 a[4], b[NW];
#pragma unroll
        for (int mi = 0; mi < 4; mi++)
            a[mi] = *(const bf16x8*)&As[(mi * 16 + mm) * LDT + q * 8];
#pragma unroll
        for (int ni = 0; ni < NW; ni++)
            b[ni] = *(const bf16x8*)&Bs[(w * NW * 16 + ni * 16 + mm) * LDT + q * 8];
#pragma unroll
        for (int mi = 0; mi < 4; mi++)
#pragma unroll
            for (int ni = 0; ni < NW; ni++)
                acc[mi][ni] = __builtin_amdgcn_mfma_f32_16x16x32_bf16(a[mi], b[ni], acc[mi][ni], 0, 0, 0);
    }

#pragma unroll
    for (int mi = 0; mi < 4; mi++)
#pragma unroll
        for (int ni = 0; ni < NW; ni++)
#pragma unroll
            for (int r = 0; r < 4; r++) {
                int row = m0 + mi * 16 + q * 4 + r;
                if (row < M)
                    C[(size_t)row * N + w * NW * 16 + ni * 16 + mm] = f2b(acc[mi][ni][r]);
            }
}

// ---------------- aggregation layer 1 ----------------
__global__ __launch_bounds__(256) void agg1_kernel(const unsigned short* __restrict__ S,
                                                   const int* __restrict__ offsets,
                                                   const uint4* __restrict__ edges,
                                                   const float* __restrict__ b1,
                                                   unsigned short* __restrict__ h, int Nn) {
    int wave = threadIdx.x >> 6;
    int lane = threadIdx.x & 63;
    int node = blockIdx.x * 4 + wave;
    if (node >= Nn) return;
    int s = offsets[node], e = offsets[node + 1];
    float a0 = 0.f, a1 = 0.f, a2 = 0.f, a3 = 0.f;
    int i = s;
    for (; i + 4 <= e; i += 4) {
        uint4 e0 = edges[i], e1 = edges[i + 1], e2 = edges[i + 2], e3 = edges[i + 3];
        ushort4 v0 = *(const ushort4*)(S + (size_t)e0.x * 256 + lane * 4);
        ushort4 v1 = *(const ushort4*)(S + (size_t)e1.x * 256 + lane * 4);
        ushort4 v2 = *(const ushort4*)(S + (size_t)e2.x * 256 + lane * 4);
        ushort4 v3 = *(const ushort4*)(S + (size_t)e3.x * 256 + lane * 4);
        float w0 = __uint_as_float(e0.y), w1 = __uint_as_float(e1.y);
        float w2 = __uint_as_float(e2.y), w3 = __uint_as_float(e3.y);
        a0 += w0 * b2f(v0.x) + w1 * b2f(v1.x) + w2 * b2f(v2.x) + w3 * b2f(v3.x);
        a1 += w0 * b2f(v0.y) + w1 * b2f(v1.y) + w2 * b2f(v2.y) + w3 * b2f(v3.y);
        a2 += w0 * b2f(v0.z) + w1 * b2f(v1.z) + w2 * b2f(v2.z) + w3 * b2f(v3.z);
        a3 += w0 * b2f(v0.w) + w1 * b2f(v1.w) + w2 * b2f(v2.w) + w3 * b2f(v3.w);
    }
    for (; i < e; i++) {
        uint4 ev = edges[i];
        float w = __uint_as_float(ev.y);
        ushort4 v = *(const ushort4*)(S + (size_t)ev.x * 256 + lane * 4);
        a0 += w * b2f(v.x); a1 += w * b2f(v.y); a2 += w * b2f(v.z); a3 += w * b2f(v.w);
    }
    float4 bb = ((const float4*)b1)[lane];
    float r0 = a0 + bb.x, r1 = a1 + bb.y, r2 = a2 + bb.z, r3 = a3 + bb.w;
    r0 = r0 > 0.f ? r0 : r0 * NEG_SLOPE;
    r1 = r1 > 0.f ? r1 : r1 * NEG_SLOPE;
    r2 = r2 > 0.f ? r2 : r2 * NEG_SLOPE;
    r3 = r3 > 0.f ? r3 : r3 * NEG_SLOPE;
    ushort4 o;
    o.x = f2b(r0); o.y = f2b(r1); o.z = f2b(r2); o.w = f2b(r3);
    *(ushort4*)&h[(size_t)node * 256 + lane * 4] = o;
}

// ---------------- aggregation layer 2 + bias + log_softmax ----------------
__global__ __launch_bounds__(256) void agg2_kernel(const unsigned short* __restrict__ S,
                                                   const int* __restrict__ offsets,
                                                   const uint4* __restrict__ edges,
                                                   const float* __restrict__ b2,
                                                   float* __restrict__ out, int Nn) {
    int wave = threadIdx.x >> 6;
    int lane = threadIdx.x & 63;
    int node = blockIdx.x * 4 + wave;
    if (node >= Nn) return;
    int s = offsets[node], e = offsets[node + 1];
    float acc = 0.f;
    int i = s;
    for (; i + 4 <= e; i += 4) {
        uint4 e0 = edges[i], e1 = edges[i + 1], e2 = edges[i + 2], e3 = edges[i + 3];
        float v0 = b2f(S[(size_t)e0.x * 64 + lane]);
        float v1 = b2f(S[(size_t)e1.x * 64 + lane]);
        float v2 = b2f(S[(size_t)e2.x * 64 + lane]);
        float v3 = b2f(S[(size_t)e3.x * 64 + lane]);
        acc += __uint_as_float(e0.z) * v0 + __uint_as_float(e1.z) * v1
             + __uint_as_float(e2.z) * v2 + __uint_as_float(e3.z) * v3;
    }
    for (; i < e; i++) {
        uint4 ev = edges[i];
        acc += __uint_as_float(ev.z) * b2f(S[(size_t)ev.x * 64 + lane]);
    }
    float logit = acc + b2[lane];
    float m = logit;
    for (int off = 32; off; off >>= 1) m = fmaxf(m, __shfl_xor(m, off));
    float ex = expf(logit - m);
    float sum = ex;
    for (int off = 32; off; off >>= 1) sum += __shfl_xor(sum, off);
    out[(size_t)node * 64 + lane] = logit - m - logf(sum);
}

// ---------------- launch ----------------
extern "C" void kernel_launch(void* const* d_in, const int* in_sizes, int n_in,
                              void* d_out, int out_size, void* d_ws, size_t ws_size,
                              hipStream_t stream) {
    const float* x    = (const float*)d_in[0];
    const int*   esrc = (const int*)d_in[1];
    const int*   edst = (const int*)d_in[2];
    const float* ew1  = (const float*)d_in[3];
    const float* ew2  = (const float*)d_in[4];
    const float* W1   = (const float*)d_in[5];
    const float* b1   = (const float*)d_in[6];
    const float* W2   = (const float*)d_in[7];
    const float* b2   = (const float*)d_in[8];
    float* out = (float*)d_out;
    const int Nn = in_sizes[0] / FAN_IN;   // 100000
    const int E  = in_sizes[1];            // 3200000
    const int NB = (Nn + NPB - 1) / NPB;   // 1563 buckets

    char* p = (char*)d_ws;
    auto alloc = [&](size_t bytes) -> char* {
        char* r = p;
        p += (bytes + 255) & ~(size_t)255;
        return r;
    };
    size_t s1_bytes = (size_t)Nn * FAN_MID * 2;       // 51.2 MB
    size_t st_bytes = (size_t)E * 16;                 // 51.2 MB
    // bstage aliases support1: bstage dead before gemm1 writes support1
    char* s1_region = alloc(s1_bytes > st_bytes ? s1_bytes : st_bytes);
    unsigned short* support1 = (unsigned short*)s1_region;
    uint4*          bstage   = (uint4*)s1_region;
    unsigned short* h        = (unsigned short*)alloc((size_t)Nn * FAN_MID * 2);  // 51.2 MB
    unsigned short* support2 = (unsigned short*)alloc((size_t)Nn * FAN_OUT * 2);  // 12.8 MB
    unsigned short* W1t      = (unsigned short*)alloc((size_t)FAN_IN * FAN_MID * 2);
    unsigned short* W2t      = (unsigned short*)alloc((size_t)FAN_MID * FAN_OUT * 2);
    int*            bcount   = (int*)alloc((size_t)NB * 4);
    int*            boff     = (int*)alloc(((size_t)NB + 1) * 4);
    int*            bcur     = (int*)alloc((size_t)NB * CURPAD * 4);
    int*            offsets  = (int*)alloc(((size_t)Nn + 1) * 4);
    uint4*          csr      = (uint4*)alloc((size_t)E * 16);                      // 51.2 MB
    // total ~168 MB

    // bucketed CSR build
    zerob_kernel<<<(NB + 255) / 256, 256, 0, stream>>>(bcount, NB);
    bhist_kernel<<<512, 256, 0, stream>>>(edst, bcount, E, NB);
    bscan_kernel<<<1, 1024, 0, stream>>>(bcount, boff, bcur, NB, E);
    bscatter_kernel<<<(E + 255) / 256, 256, 0, stream>>>(esrc, edst, ew1, ew2, bcur, bstage, E);
    bsort_kernel<<<NB, 256, 0, stream>>>(bstage, boff, offsets, csr, Nn, E, NB);

    // weights: transpose + bf16
    convert_w_kernel<<<(FAN_IN * FAN_MID + 255) / 256, 256, 0, stream>>>(W1, W1t, FAN_IN, FAN_MID);
    convert_w_kernel<<<(FAN_MID * FAN_OUT + 255) / 256, 256, 0, stream>>>(W2, W2t, FAN_MID, FAN_OUT);

    // layer 1: support1 = bf16(x @ W1)  (overwrites bstage region — bstage is dead now)
    gemm_bt<FAN_IN, FAN_MID, true><<<dim3((Nn + 63) / 64, 1), 256, 0, stream>>>(
        x, W1t, support1, Nn);
    agg1_kernel<<<(Nn + 3) / 4, 256, 0, stream>>>(support1, offsets, csr, b1, h, Nn);

    // layer 2: support2 = bf16(h @ W2)
    gemm_bt<FAN_MID, FAN_OUT, false><<<dim3((Nn + 63) / 64, 1), 256, 0, stream>>>(
        h, W2t, support2, Nn);
    agg2_kernel<<<(Nn + 3) / 4, 256, 0, stream>>>(support2, offsets, csr, b2, out, Nn);
}

// Round 4
// 865.245 us; speedup vs baseline: 2.0259x; 1.1387x over previous
//
#include <hip/hip_runtime.h>
#include <stdint.h>

#define FAN_IN  512
#define FAN_MID 256
#define FAN_OUT 64
#define NEG_SLOPE 0.01f
#define NPB 128         // nodes per bucket (bucket = dst >> 7)
#define MAXNB 1024      // LDS bound for bucket arrays (supports Nn <= 131072)
#define BPART 256       // partition blocks (= part_scan blockDim)

typedef __bf16 bf16_t;
typedef bf16_t bf16x8 __attribute__((ext_vector_type(8)));
typedef float  f32x4  __attribute__((ext_vector_type(4)));
typedef unsigned short u16x8 __attribute__((ext_vector_type(8)));

__device__ inline unsigned short f2b(float f) {
    union { float f; unsigned int u; } v; v.f = f;
    unsigned int u = v.u;
    return (unsigned short)((u + 0x7fffu + ((u >> 16) & 1u)) >> 16); // RNE
}
__device__ inline float b2f(unsigned short u) {
    union { unsigned int u; float f; } v; v.u = ((unsigned int)u) << 16; return v.f;
}

// ---------------- deterministic bucketed partition ----------------
__global__ void zerob_kernel(int* p, int n) {
    int i = blockIdx.x * 256 + threadIdx.x;
    if (i < n) p[i] = 0;
}

// per-block LDS histogram -> gcount[blk][bucket] (block-major) + bucket totals
__global__ __launch_bounds__(256) void part_hist(const int* __restrict__ dst,
                                                 int* __restrict__ gcount,
                                                 int* __restrict__ bcount,
                                                 int E, int nb, int chunk) {
    __shared__ int lc[MAXNB];
    int blk = blockIdx.x;
    for (int i = threadIdx.x; i < nb; i += 256) lc[i] = 0;
    __syncthreads();
    int s = blk * chunk;
    int e = s + chunk; if (e > E) e = E;
    for (int i = s + threadIdx.x; i < e; i += 256)
        atomicAdd(&lc[dst[i] >> 7], 1);
    __syncthreads();
    for (int i = threadIdx.x; i < nb; i += 256) {
        int c = lc[i];
        gcount[blk * nb + i] = c;
        if (c) atomicAdd(&bcount[i], c);
    }
}

// single-block scan over bucket totals -> boff
__global__ void bscan_kernel(const int* __restrict__ bcount, int* __restrict__ boff,
                             int nb, int E) {
    __shared__ int part[1024];
    int t = threadIdx.x;
    int chunk = (nb + 1023) >> 10;
    int s = t * chunk;
    int e = s + chunk; if (e > nb) e = nb;
    int sum = 0;
    for (int i = s; i < e; i++) sum += bcount[i];
    part[t] = sum;
    __syncthreads();
    for (int off = 1; off < 1024; off <<= 1) {
        int v = (t >= off) ? part[t - off] : 0;
        __syncthreads();
        part[t] += v;
        __syncthreads();
    }
    int run = (t == 0) ? 0 : part[t - 1];
    for (int i = s; i < e; i++) {
        boff[i] = run;
        run += bcount[i];
    }
    if (t == 1023) boff[nb] = E;
}

// one block per bucket: exclusive scan of the BPART per-block counts -> gbase[blk][bucket]
__global__ __launch_bounds__(BPART) void part_scan(const int* __restrict__ gcount,
                                                   const int* __restrict__ boff,
                                                   int* __restrict__ gbase, int nb) {
    __shared__ int v[BPART];
    int bucket = blockIdx.x;
    int t = threadIdx.x;
    int val = gcount[t * nb + bucket];
    v[t] = val;
    __syncthreads();
    for (int off = 1; off < BPART; off <<= 1) {
        int x = (t >= off) ? v[t - off] : 0;
        __syncthreads();
        v[t] += x;
        __syncthreads();
    }
    gbase[t * nb + bucket] = (t == 0 ? 0 : v[t - 1]) + boff[bucket];
}

// each block re-reads its chunk; positions from LDS cursors seeded with gbase.
// All records of a (block,bucket) run are written by ONE block -> lines fill in one L2.
__global__ __launch_bounds__(256) void part_scatter(const int* __restrict__ src,
                                                    const int* __restrict__ dst,
                                                    const float* __restrict__ w1,
                                                    const float* __restrict__ w2,
                                                    const int* __restrict__ gbase,
                                                    uint4* __restrict__ bstage,
                                                    int E, int nb, int chunk) {
    __shared__ int lcur[MAXNB];
    int blk = blockIdx.x;
    for (int i = threadIdx.x; i < nb; i += 256) lcur[i] = gbase[blk * nb + i];
    __syncthreads();
    int s = blk * chunk;
    int e = s + chunk; if (e > E) e = E;
    for (int i = s + threadIdx.x; i < e; i += 256) {
        int d = dst[i];
        int pos = atomicAdd(&lcur[d >> 7], 1);
        uint4 v;
        v.x = (unsigned int)src[i];
        v.y = __float_as_uint(w1[i]);
        v.z = __float_as_uint(w2[i]);
        v.w = (unsigned int)d;
        bstage[pos] = v;
    }
}

// one block per bucket: LDS count+scan (emits offsets[] for free), local re-scatter.
__global__ __launch_bounds__(256) void bsort_kernel(const uint4* __restrict__ bstage,
                                                    const int* __restrict__ boff,
                                                    int* __restrict__ offsets,
                                                    uint4* __restrict__ csr,
                                                    int Nn, int E, int nb) {
    __shared__ int cnt[NPB];
    __shared__ int scn[NPB];
    __shared__ int cur[NPB];
    int b = blockIdx.x;
    int t = threadIdx.x;
    int base = boff[b], end = boff[b + 1];
    int n0 = b * NPB;
    if (t < NPB) cnt[t] = 0;
    __syncthreads();
    for (int i = base + t; i < end; i += 256)
        atomicAdd(&cnt[bstage[i].w - n0], 1);
    __syncthreads();
    if (t == 0) {
        int run = 0;
        for (int j = 0; j < NPB; j++) { scn[j] = run; run += cnt[j]; }
    }
    __syncthreads();
    if (t < NPB) {
        cur[t] = scn[t];
        int n = n0 + t;
        if (n < Nn) offsets[n] = base + scn[t];
    }
    if (b == nb - 1 && t == 0) offsets[Nn] = E;
    __syncthreads();
    for (int i = base + t; i < end; i += 256) {
        uint4 rec = bstage[i];
        int lp = atomicAdd(&cur[rec.w - n0], 1);
        csr[base + lp] = rec;
    }
}

// ---------------- weight transpose + bf16 convert: Wt[n][k] = bf16(W[k][n]) ----------------
__global__ void convert_w_kernel(const float* __restrict__ W, unsigned short* __restrict__ Wt,
                                 int K, int N) {
    int idx = blockIdx.x * 256 + threadIdx.x;
    if (idx >= K * N) return;
    int k = idx / N, n = idx % N;
    Wt[(size_t)n * K + k] = f2b(W[idx]);
}

// ---------------- bf16 MFMA GEMM: C[M,N] = A[M,K] * Bt[N,K]^T, C in bf16 ----------------
template<int K, int N, bool A_F32>
__global__ __launch_bounds__(256) void gemm_bt(const void* __restrict__ Ap,
                                               const unsigned short* __restrict__ Bt,
                                               unsigned short* __restrict__ C, int M) {
    constexpr int LDT = 40;
    constexpr int NW  = N / 64;
    __shared__ unsigned short As[64 * LDT];
    __shared__ unsigned short Bs[N * LDT];
    const int m0   = blockIdx.x * 64;
    const int tid  = threadIdx.x;
    const int lane = tid & 63;
    const int w    = tid >> 6;
    const int lrow = tid >> 2;
    const int lseg = (tid & 3) * 8;
    const int q    = lane >> 4;
    const int mm   = lane & 15;

    f32x4 acc[4][NW] = {};

    for (int k0 = 0; k0 < K; k0 += 32) {
        __syncthreads();
        {
            int gm = m0 + lrow;
            u16x8 av;
            if (A_F32) {
                const float* A32 = (const float*)Ap;
                if (gm < M) {
                    const float4* pp = (const float4*)(A32 + (size_t)gm * K + k0 + lseg);
                    float4 f0 = pp[0], f1 = pp[1];
                    av[0] = f2b(f0.x); av[1] = f2b(f0.y); av[2] = f2b(f0.z); av[3] = f2b(f0.w);
                    av[4] = f2b(f1.x); av[5] = f2b(f1.y); av[6] = f2b(f1.z); av[7] = f2b(f1.w);
                } else av = (u16x8)0;
            } else {
                const unsigned short* A16 = (const unsigned short*)Ap;
                if (gm < M) av = *(const u16x8*)(A16 + (size_t)gm * K + k0 + lseg);
                else        av = (u16x8)0;
            }
            *(u16x8*)&As[lrow * LDT + lseg] = av;
        }
#pragma unroll
        for (int r = 0; r < N / 64; r++) {
            int nr = r * 64 + lrow;
            *(u16x8*)&Bs[nr * LDT + lseg] =
                *(const u16x8*)(Bt + (size_t)nr * K + k0 + lseg);
        }
        __syncthreads();

        bf16x8 a[4], b[NW];
#pragma unroll
        for (int mi = 0; mi < 4; mi++)
            a[mi] = *(const bf16x8*)&As[(mi * 16 + mm) * LDT + q * 8];
#pragma unroll
        for (int ni = 0; ni < NW; ni++)
            b[ni] = *(const bf16x8*)&Bs[(w * NW * 16 + ni * 16 + mm) * LDT + q * 8];
#pragma unroll
        for (int mi = 0; mi < 4; mi++)
#pragma unroll
            for (int ni = 0; ni < NW; ni++)
                acc[mi][ni] = __builtin_amdgcn_mfma_f32_16x16x32_bf16(a[mi], b[ni], acc[mi][ni], 0, 0, 0);
    }

#pragma unroll
    for (int mi = 0; mi < 4; mi++)
#pragma unroll
        for (int ni = 0; ni < NW; ni++)
#pragma unroll
            for (int r = 0; r < 4; r++) {
                int row = m0 + mi * 16 + q * 4 + r;
                if (row < M)
                    C[(size_t)row * N + w * NW * 16 + ni * 16 + mm] = f2b(acc[mi][ni][r]);
            }
}

// ---------------- aggregation layer 1 ----------------
__global__ __launch_bounds__(256) void agg1_kernel(const unsigned short* __restrict__ S,
                                                   const int* __restrict__ offsets,
                                                   const uint4* __restrict__ edges,
                                                   const float* __restrict__ b1,
                                                   unsigned short* __restrict__ h, int Nn) {
    int wave = threadIdx.x >> 6;
    int lane = threadIdx.x & 63;
    int node = blockIdx.x * 4 + wave;
    if (node >= Nn) return;
    int s = offsets[node], e = offsets[node + 1];
    float a0 = 0.f, a1 = 0.f, a2 = 0.f, a3 = 0.f;
    int i = s;
    for (; i + 4 <= e; i += 4) {
        uint4 e0 = edges[i], e1 = edges[i + 1], e2 = edges[i + 2], e3 = edges[i + 3];
        ushort4 v0 = *(const ushort4*)(S + (size_t)e0.x * 256 + lane * 4);
        ushort4 v1 = *(const ushort4*)(S + (size_t)e1.x * 256 + lane * 4);
        ushort4 v2 = *(const ushort4*)(S + (size_t)e2.x * 256 + lane * 4);
        ushort4 v3 = *(const ushort4*)(S + (size_t)e3.x * 256 + lane * 4);
        float w0 = __uint_as_float(e0.y), w1 = __uint_as_float(e1.y);
        float w2 = __uint_as_float(e2.y), w3 = __uint_as_float(e3.y);
        a0 += w0 * b2f(v0.x) + w1 * b2f(v1.x) + w2 * b2f(v2.x) + w3 * b2f(v3.x);
        a1 += w0 * b2f(v0.y) + w1 * b2f(v1.y) + w2 * b2f(v2.y) + w3 * b2f(v3.y);
        a2 += w0 * b2f(v0.z) + w1 * b2f(v1.z) + w2 * b2f(v2.z) + w3 * b2f(v3.z);
        a3 += w0 * b2f(v0.w) + w1 * b2f(v1.w) + w2 * b2f(v2.w) + w3 * b2f(v3.w);
    }
    for (; i < e; i++) {
        uint4 ev = edges[i];
        float w = __uint_as_float(ev.y);
        ushort4 v = *(const ushort4*)(S + (size_t)ev.x * 256 + lane * 4);
        a0 += w * b2f(v.x); a1 += w * b2f(v.y); a2 += w * b2f(v.z); a3 += w * b2f(v.w);
    }
    float4 bb = ((const float4*)b1)[lane];
    float r0 = a0 + bb.x, r1 = a1 + bb.y, r2 = a2 + bb.z, r3 = a3 + bb.w;
    r0 = r0 > 0.f ? r0 : r0 * NEG_SLOPE;
    r1 = r1 > 0.f ? r1 : r1 * NEG_SLOPE;
    r2 = r2 > 0.f ? r2 : r2 * NEG_SLOPE;
    r3 = r3 > 0.f ? r3 : r3 * NEG_SLOPE;
    ushort4 o;
    o.x = f2b(r0); o.y = f2b(r1); o.z = f2b(r2); o.w = f2b(r3);
    *(ushort4*)&h[(size_t)node * 256 + lane * 4] = o;
}

// ---------------- aggregation layer 2 + bias + log_softmax ----------------
__global__ __launch_bounds__(256) void agg2_kernel(const unsigned short* __restrict__ S,
                                                   const int* __restrict__ offsets,
                                                   const uint4* __restrict__ edges,
                                                   const float* __restrict__ b2,
                                                   float* __restrict__ out, int Nn) {
    int wave = threadIdx.x >> 6;
    int lane = threadIdx.x & 63;
    int node = blockIdx.x * 4 + wave;
    if (node >= Nn) return;
    int s = offsets[node], e = offsets[node + 1];
    float acc = 0.f;
    int i = s;
    for (; i + 4 <= e; i += 4) {
        uint4 e0 = edges[i], e1 = edges[i + 1], e2 = edges[i + 2], e3 = edges[i + 3];
        float v0 = b2f(S[(size_t)e0.x * 64 + lane]);
        float v1 = b2f(S[(size_t)e1.x * 64 + lane]);
        float v2 = b2f(S[(size_t)e2.x * 64 + lane]);
        float v3 = b2f(S[(size_t)e3.x * 64 + lane]);
        acc += __uint_as_float(e0.z) * v0 + __uint_as_float(e1.z) * v1
             + __uint_as_float(e2.z) * v2 + __uint_as_float(e3.z) * v3;
    }
    for (; i < e; i++) {
        uint4 ev = edges[i];
        acc += __uint_as_float(ev.z) * b2f(S[(size_t)ev.x * 64 + lane]);
    }
    float logit = acc + b2[lane];
    float m = logit;
    for (int off = 32; off; off >>= 1) m = fmaxf(m, __shfl_xor(m, off));
    float ex = expf(logit - m);
    float sum = ex;
    for (int off = 32; off; off >>= 1) sum += __shfl_xor(sum, off);
    out[(size_t)node * 64 + lane] = logit - m - logf(sum);
}

// ---------------- launch ----------------
extern "C" void kernel_launch(void* const* d_in, const int* in_sizes, int n_in,
                              void* d_out, int out_size, void* d_ws, size_t ws_size,
                              hipStream_t stream) {
    const float* x    = (const float*)d_in[0];
    const int*   esrc = (const int*)d_in[1];
    const int*   edst = (const int*)d_in[2];
    const float* ew1  = (const float*)d_in[3];
    const float* ew2  = (const float*)d_in[4];
    const float* W1   = (const float*)d_in[5];
    const float* b1   = (const float*)d_in[6];
    const float* W2   = (const float*)d_in[7];
    const float* b2   = (const float*)d_in[8];
    float* out = (float*)d_out;
    const int Nn = in_sizes[0] / FAN_IN;   // 100000
    const int E  = in_sizes[1];            // 3200000
    const int NB = (Nn + NPB - 1) / NPB;   // 782 buckets
    const int chunk = (E + BPART - 1) / BPART;

    char* p = (char*)d_ws;
    auto alloc = [&](size_t bytes) -> char* {
        char* r = p;
        p += (bytes + 255) & ~(size_t)255;
        return r;
    };
    size_t s1_bytes = (size_t)Nn * FAN_MID * 2;       // 51.2 MB
    size_t st_bytes = (size_t)E * 16;                 // 51.2 MB
    // bstage aliases support1: bstage dead before gemm1 writes support1
    char* s1_region = alloc(s1_bytes > st_bytes ? s1_bytes : st_bytes);
    unsigned short* support1 = (unsigned short*)s1_region;
    uint4*          bstage   = (uint4*)s1_region;
    unsigned short* h        = (unsigned short*)alloc((size_t)Nn * FAN_MID * 2);  // 51.2 MB
    unsigned short* support2 = (unsigned short*)alloc((size_t)Nn * FAN_OUT * 2);  // 12.8 MB
    unsigned short* W1t      = (unsigned short*)alloc((size_t)FAN_IN * FAN_MID * 2);
    unsigned short* W2t      = (unsigned short*)alloc((size_t)FAN_MID * FAN_OUT * 2);
    int*            bcount   = (int*)alloc((size_t)NB * 4);
    int*            boff     = (int*)alloc(((size_t)NB + 1) * 4);
    int*            gcount   = (int*)alloc((size_t)BPART * NB * 4);               // 0.8 MB
    int*            gbase    = (int*)alloc((size_t)BPART * NB * 4);               // 0.8 MB
    int*            offsets  = (int*)alloc(((size_t)Nn + 1) * 4);
    uint4*          csr      = (uint4*)alloc((size_t)E * 16);                      // 51.2 MB
    // total ~170 MB

    // deterministic bucketed CSR build
    zerob_kernel<<<(NB + 255) / 256, 256, 0, stream>>>(bcount, NB);
    part_hist<<<BPART, 256, 0, stream>>>(edst, gcount, bcount, E, NB, chunk);
    bscan_kernel<<<1, 1024, 0, stream>>>(bcount, boff, NB, E);
    part_scan<<<NB, BPART, 0, stream>>>(gcount, boff, gbase, NB);
    part_scatter<<<BPART, 256, 0, stream>>>(esrc, edst, ew1, ew2, gbase, bstage, E, NB, chunk);
    bsort_kernel<<<NB, 256, 0, stream>>>(bstage, boff, offsets, csr, Nn, E, NB);

    // weights: transpose + bf16
    convert_w_kernel<<<(FAN_IN * FAN_MID + 255) / 256, 256, 0, stream>>>(W1, W1t, FAN_IN, FAN_MID);
    convert_w_kernel<<<(FAN_MID * FAN_OUT + 255) / 256, 256, 0, stream>>>(W2, W2t, FAN_MID, FAN_OUT);

    // layer 1: support1 = bf16(x @ W1)  (overwrites bstage region — dead now)
    gemm_bt<FAN_IN, FAN_MID, true><<<dim3((Nn + 63) / 64, 1), 256, 0, stream>>>(
        x, W1t, support1, Nn);
    agg1_kernel<<<(Nn + 3) / 4, 256, 0, stream>>>(support1, offsets, csr, b1, h, Nn);

    // layer 2: support2 = bf16(h @ W2)
    gemm_bt<FAN_MID, FAN_OUT, false><<<dim3((Nn + 63) / 64, 1), 256, 0, stream>>>(
        h, W2t, support2, Nn);
    agg2_kernel<<<(Nn + 3) / 4, 256, 0, stream>>>(support2, offsets, csr, b2, out, Nn);
}